// Round 1
// baseline (921.464 us; speedup 1.0000x reference)
//
#include <hip/hip_runtime.h>
#include <math.h>

#define N_NODES 50000
#define N_EDGES 400000
#define F_IN    64
#define HID     128
#define FIN     192   /* F_IN + HID */
#define RU      256   /* 2*HID */

/* ws layout (float offsets) */
#define AGGX_OFF 65536
#define AGGS_OFF (AGGX_OFF + N_NODES * F_IN)
#define WS_FLOATS (AGGS_OFF + N_NODES * HID)

/* ---------------- edge scatter: deg + agg_x + agg_s ---------------- */
__global__ void k_scatter1(const int* __restrict__ src, const int* __restrict__ dst,
                           const float* __restrict__ x, const float* __restrict__ s,
                           float* __restrict__ deg, float* __restrict__ agg_x,
                           float* __restrict__ agg_s) {
    const int lane   = threadIdx.x & 63;
    const int wave   = (blockIdx.x * blockDim.x + threadIdx.x) >> 6;
    const int nwaves = (gridDim.x * blockDim.x) >> 6;
    for (int e = wave; e < N_EDGES; e += nwaves) {
        const int se = src[e];
        const int de = dst[e];
        if (lane == 0) atomicAdd(&deg[de], 1.0f);
        atomicAdd(&agg_x[de * F_IN + lane], x[(size_t)se * F_IN + lane]);
        atomicAdd(&agg_s[de * HID + lane],       s[(size_t)se * HID + lane]);
        atomicAdd(&agg_s[de * HID + 64 + lane],  s[(size_t)se * HID + 64 + lane]);
    }
}

/* ---------------- edge scatter: agg_rs = sum r[s]*states[s] ---------------- */
__global__ void k_scatter2(const int* __restrict__ src, const int* __restrict__ dst,
                           const float* __restrict__ r, const float* __restrict__ s,
                           float* __restrict__ agg_rs) {
    const int lane   = threadIdx.x & 63;
    const int wave   = (blockIdx.x * blockDim.x + threadIdx.x) >> 6;
    const int nwaves = (gridDim.x * blockDim.x) >> 6;
    for (int e = wave; e < N_EDGES; e += nwaves) {
        const int se = src[e];
        const int de = dst[e];
        const size_t b = (size_t)se * HID;
        atomicAdd(&agg_rs[de * HID + lane],      r[b + lane] * s[b + lane]);
        atomicAdd(&agg_rs[de * HID + 64 + lane], r[b + 64 + lane] * s[b + 64 + lane]);
    }
}

/* ---------------- GEMM 1: [agg_x, agg_s]/deg @ W_ru + b_ru -> sigmoid -> r,u ----- */
#define NB 8   /* nodes per block */
__global__ void k_gemm_ru(const float* __restrict__ agg_x, const float* __restrict__ agg_s,
                          const float* __restrict__ deg, const float* __restrict__ W,
                          const float* __restrict__ b, float* __restrict__ r_out,
                          float* __restrict__ u_out) {
    __shared__ float a[NB][FIN];
    const int n0 = blockIdx.x * NB;
    const int t  = threadIdx.x;

    for (int i = t; i < NB * FIN; i += 256) {
        const int nl = i / FIN, k = i % FIN;
        const int n = n0 + nl;
        float v = 0.f;
        if (n < N_NODES) {
            const float d = fmaxf(deg[n], 1.0f);
            v = (k < F_IN ? agg_x[(size_t)n * F_IN + k]
                          : agg_s[(size_t)n * HID + (k - F_IN)]) / d;
        }
        a[nl][k] = v;
    }
    __syncthreads();

    const int nl   = t >> 5;       /* 0..7  */
    const int cg   = t & 31;       /* 0..31 */
    const int col0 = cg * 8;       /* 8 cols per thread, 256 cols total */
    float acc[8] = {0.f, 0.f, 0.f, 0.f, 0.f, 0.f, 0.f, 0.f};

    for (int k = 0; k < FIN; ++k) {
        const float av = a[nl][k];
        const float4* wp = (const float4*)(W + (size_t)k * RU + col0);
        const float4 w0 = wp[0];
        const float4 w1 = wp[1];
        acc[0] += av * w0.x; acc[1] += av * w0.y;
        acc[2] += av * w0.z; acc[3] += av * w0.w;
        acc[4] += av * w1.x; acc[5] += av * w1.y;
        acc[6] += av * w1.z; acc[7] += av * w1.w;
    }

    const int n = n0 + nl;
    if (n < N_NODES) {
        #pragma unroll
        for (int j = 0; j < 8; ++j) {
            const int col = col0 + j;
            float v = acc[j] + b[col];
            v = 1.f / (1.f + expf(-v));
            if (col < HID) r_out[(size_t)n * HID + col] = v;
            else           u_out[(size_t)n * HID + (col - HID)] = v;
        }
    }
}

/* ---------------- GEMM 2: [agg_x, agg_rs]/deg @ W_c + b_c -> tanh -> gate ------- */
__global__ void k_gemm_c(const float* __restrict__ agg_x, const float* __restrict__ agg_rs,
                         const float* __restrict__ deg, const float* __restrict__ W,
                         const float* __restrict__ b, const float* __restrict__ states,
                         const float* __restrict__ u_in, float* __restrict__ out1,
                         float* __restrict__ out2) {
    __shared__ float a[NB][FIN];
    const int n0 = blockIdx.x * NB;
    const int t  = threadIdx.x;

    for (int i = t; i < NB * FIN; i += 256) {
        const int nl = i / FIN, k = i % FIN;
        const int n = n0 + nl;
        float v = 0.f;
        if (n < N_NODES) {
            const float d = fmaxf(deg[n], 1.0f);
            v = (k < F_IN ? agg_x[(size_t)n * F_IN + k]
                          : agg_rs[(size_t)n * HID + (k - F_IN)]) / d;
        }
        a[nl][k] = v;
    }
    __syncthreads();

    const int nl   = t >> 5;
    const int cg   = t & 31;
    const int col0 = cg * 4;       /* 4 cols per thread, 128 cols total */
    float acc[4] = {0.f, 0.f, 0.f, 0.f};

    for (int k = 0; k < FIN; ++k) {
        const float av = a[nl][k];
        const float4 w = *(const float4*)(W + (size_t)k * HID + col0);
        acc[0] += av * w.x; acc[1] += av * w.y;
        acc[2] += av * w.z; acc[3] += av * w.w;
    }

    const int n = n0 + nl;
    if (n < N_NODES) {
        #pragma unroll
        for (int j = 0; j < 4; ++j) {
            const int col = col0 + j;
            const size_t idx = (size_t)n * HID + col;
            const float c  = tanhf(acc[j] + b[col]);
            const float u  = u_in[idx];
            const float st = states[idx];
            const float ns = u * st + (1.f - u) * c;
            out1[idx] = ns;
            out2[idx] = ns;
        }
    }
}

extern "C" void kernel_launch(void* const* d_in, const int* in_sizes, int n_in,
                              void* d_out, int out_size, void* d_ws, size_t ws_size,
                              hipStream_t stream) {
    const float* inputs = (const float*)d_in[0];
    const float* states = (const float*)d_in[1];
    const int*   ei     = (const int*)d_in[2];
    const float* W_ru   = (const float*)d_in[3];
    const float* b_ru   = (const float*)d_in[4];
    const float* W_c    = (const float*)d_in[5];
    const float* b_c    = (const float*)d_in[6];

    float* out  = (float*)d_out;
    float* out1 = out;                             /* holds r, then new_state */
    float* out2 = out + (size_t)N_NODES * HID;     /* holds u, then new_state */

    float* ws    = (float*)d_ws;
    float* deg   = ws;
    float* agg_x = ws + AGGX_OFF;
    float* agg_s = ws + AGGS_OFF;                  /* reused as agg_rs */

    const int* src = ei;
    const int* dst = ei + N_EDGES;

    hipMemsetAsync(ws, 0, (size_t)WS_FLOATS * sizeof(float), stream);
    k_scatter1<<<2048, 256, 0, stream>>>(src, dst, inputs, states, deg, agg_x, agg_s);
    k_gemm_ru<<<N_NODES / NB, 256, 0, stream>>>(agg_x, agg_s, deg, W_ru, b_ru, out1, out2);
    hipMemsetAsync(agg_s, 0, (size_t)N_NODES * HID * sizeof(float), stream);
    k_scatter2<<<2048, 256, 0, stream>>>(src, dst, out1, states, agg_s);
    k_gemm_c<<<N_NODES / NB, 256, 0, stream>>>(agg_x, agg_s, deg, W_c, b_c, states,
                                               out2, out1, out2);
}

// Round 2
// 655.238 us; speedup vs baseline: 1.4063x; 1.4063x over previous
//
#include <hip/hip_runtime.h>
#include <math.h>

#define N_NODES 50000
#define N_EDGES 400000
#define F_IN    64
#define HID     128
#define FIN     192   /* F_IN + HID */
#define RU      256   /* 2*HID */

/* ws layout (float offsets) */
#define AGGX_OFF 65536
#define AGGS_OFF (AGGX_OFF + N_NODES * F_IN)
#define WS_FLOATS (AGGS_OFF + N_NODES * HID)

#define NBR 64        /* nodes per block in GEMM row tile */
#define ATP 68        /* padded row length of transposed A tile (16B-aligned, low bank conflict) */

__device__ __forceinline__ float sigf(float x) { return 1.f / (1.f + expf(-x)); }

/* ---------------- edge scatter: deg + agg_x + agg_s ---------------- */
__global__ void k_scatter1(const int* __restrict__ src, const int* __restrict__ dst,
                           const float* __restrict__ x, const float* __restrict__ s,
                           float* __restrict__ deg, float* __restrict__ agg_x,
                           float* __restrict__ agg_s) {
    const int lane   = threadIdx.x & 63;
    const int wave   = (blockIdx.x * blockDim.x + threadIdx.x) >> 6;
    const int nwaves = (gridDim.x * blockDim.x) >> 6;
    for (int e = wave; e < N_EDGES; e += nwaves) {
        const int se = src[e];
        const int de = dst[e];
        if (lane == 0) atomicAdd(&deg[de], 1.0f);
        atomicAdd(&agg_x[de * F_IN + lane], x[(size_t)se * F_IN + lane]);
        atomicAdd(&agg_s[de * HID + lane],       s[(size_t)se * HID + lane]);
        atomicAdd(&agg_s[de * HID + 64 + lane],  s[(size_t)se * HID + 64 + lane]);
    }
}

/* ---------------- edge scatter: agg_rs = sum r[s]*states[s] ---------------- */
__global__ void k_scatter2(const int* __restrict__ src, const int* __restrict__ dst,
                           const float* __restrict__ r, const float* __restrict__ s,
                           float* __restrict__ agg_rs) {
    const int lane   = threadIdx.x & 63;
    const int wave   = (blockIdx.x * blockDim.x + threadIdx.x) >> 6;
    const int nwaves = (gridDim.x * blockDim.x) >> 6;
    for (int e = wave; e < N_EDGES; e += nwaves) {
        const int se = src[e];
        const int de = dst[e];
        const size_t b = (size_t)se * HID;
        atomicAdd(&agg_rs[de * HID + lane],      r[b + lane] * s[b + lane]);
        atomicAdd(&agg_rs[de * HID + 64 + lane], r[b + 64 + lane] * s[b + 64 + lane]);
    }
}

/* ------- GEMM 1: [agg_x, agg_s]/deg @ W_ru + b_ru -> sigmoid -> r,u -------
 * 64 nodes/block, 256 threads. Thread tile: 16 rows x 4 cols (64 acc).
 * A is staged TRANSPOSED in LDS: At[k][node] so the inner loop reads A via
 * wave-broadcast ds_read_b128 and W via coalesced float4 from L2.          */
__global__ __launch_bounds__(256) void k_gemm_ru(
        const float* __restrict__ agg_x, const float* __restrict__ agg_s,
        const float* __restrict__ deg, const float* __restrict__ W,
        const float* __restrict__ b, float* __restrict__ r_out,
        float* __restrict__ u_out) {
    __shared__ float At[FIN][ATP];
    __shared__ float inv[NBR];
    const int n0 = blockIdx.x * NBR;
    const int t  = threadIdx.x;

    if (t < NBR) {
        const int n = n0 + t;
        inv[t] = (n < N_NODES) ? 1.0f / fmaxf(deg[n], 1.0f) : 0.f;
    }
    __syncthreads();

    for (int i = t; i < NBR * FIN; i += 256) {
        const int nl = i / FIN, k = i - nl * FIN;
        const int n  = n0 + nl;
        float v = 0.f;
        if (n < N_NODES)
            v = (k < F_IN ? agg_x[(size_t)n * F_IN + k]
                          : agg_s[(size_t)n * HID + (k - F_IN)]) * inv[nl];
        At[k][nl] = v;
    }
    __syncthreads();

    const int col0 = (t & 63) * 4;        /* 64 col-groups cover 256 cols */
    const int r0   = (t >> 6) * 16;       /* 4 row-groups of 16 rows      */
    float acc[16][4] = {};

    const float* Wk = W + col0;
    for (int k = 0; k < FIN; ++k) {
        const float4 w = *(const float4*)Wk;
        Wk += RU;
        float a[16];
        float4 av;
        av = *(const float4*)(&At[k][r0]);      a[0]=av.x; a[1]=av.y; a[2]=av.z; a[3]=av.w;
        av = *(const float4*)(&At[k][r0 + 4]);  a[4]=av.x; a[5]=av.y; a[6]=av.z; a[7]=av.w;
        av = *(const float4*)(&At[k][r0 + 8]);  a[8]=av.x; a[9]=av.y; a[10]=av.z; a[11]=av.w;
        av = *(const float4*)(&At[k][r0 + 12]); a[12]=av.x; a[13]=av.y; a[14]=av.z; a[15]=av.w;
        #pragma unroll
        for (int r = 0; r < 16; ++r) {
            acc[r][0] = fmaf(a[r], w.x, acc[r][0]);
            acc[r][1] = fmaf(a[r], w.y, acc[r][1]);
            acc[r][2] = fmaf(a[r], w.z, acc[r][2]);
            acc[r][3] = fmaf(a[r], w.w, acc[r][3]);
        }
    }

    const float4 bb = *(const float4*)(b + col0);
    float* outp;
    int colrel;
    if (col0 < HID) { outp = r_out; colrel = col0; }
    else            { outp = u_out; colrel = col0 - HID; }

    #pragma unroll
    for (int r = 0; r < 16; ++r) {
        const int n = n0 + r0 + r;
        if (n < N_NODES) {
            float4 v;
            v.x = sigf(acc[r][0] + bb.x);
            v.y = sigf(acc[r][1] + bb.y);
            v.z = sigf(acc[r][2] + bb.z);
            v.w = sigf(acc[r][3] + bb.w);
            *(float4*)(&outp[(size_t)n * HID + colrel]) = v;
        }
    }
}

/* ------- GEMM 2: [agg_x, agg_rs]/deg @ W_c + b_c -> tanh -> gate -------
 * 64 nodes/block, 256 threads. Thread tile: 8 rows x 4 cols (32 acc).    */
__global__ __launch_bounds__(256) void k_gemm_c(
        const float* __restrict__ agg_x, const float* __restrict__ agg_rs,
        const float* __restrict__ deg, const float* __restrict__ W,
        const float* __restrict__ b, const float* __restrict__ states,
        const float* __restrict__ u_in, float* __restrict__ out1,
        float* __restrict__ out2) {
    __shared__ float At[FIN][ATP];
    __shared__ float inv[NBR];
    const int n0 = blockIdx.x * NBR;
    const int t  = threadIdx.x;

    if (t < NBR) {
        const int n = n0 + t;
        inv[t] = (n < N_NODES) ? 1.0f / fmaxf(deg[n], 1.0f) : 0.f;
    }
    __syncthreads();

    for (int i = t; i < NBR * FIN; i += 256) {
        const int nl = i / FIN, k = i - nl * FIN;
        const int n  = n0 + nl;
        float v = 0.f;
        if (n < N_NODES)
            v = (k < F_IN ? agg_x[(size_t)n * F_IN + k]
                          : agg_rs[(size_t)n * HID + (k - F_IN)]) * inv[nl];
        At[k][nl] = v;
    }
    __syncthreads();

    const int col0 = (t & 31) * 4;        /* 32 col-groups cover 128 cols */
    const int r0   = (t >> 5) * 8;        /* 8 row-groups of 8 rows       */
    float acc[8][4] = {};

    const float* Wk = W + col0;
    for (int k = 0; k < FIN; ++k) {
        const float4 w = *(const float4*)Wk;
        Wk += HID;
        float a[8];
        float4 av;
        av = *(const float4*)(&At[k][r0]);      a[0]=av.x; a[1]=av.y; a[2]=av.z; a[3]=av.w;
        av = *(const float4*)(&At[k][r0 + 4]);  a[4]=av.x; a[5]=av.y; a[6]=av.z; a[7]=av.w;
        #pragma unroll
        for (int r = 0; r < 8; ++r) {
            acc[r][0] = fmaf(a[r], w.x, acc[r][0]);
            acc[r][1] = fmaf(a[r], w.y, acc[r][1]);
            acc[r][2] = fmaf(a[r], w.z, acc[r][2]);
            acc[r][3] = fmaf(a[r], w.w, acc[r][3]);
        }
    }

    const float4 bb = *(const float4*)(b + col0);
    #pragma unroll
    for (int r = 0; r < 8; ++r) {
        const int n = n0 + r0 + r;
        if (n < N_NODES) {
            const size_t idx = (size_t)n * HID + col0;
            const float4 st = *(const float4*)(states + idx);
            const float4 uu = *(const float4*)(u_in + idx);
            float4 v;
            v.x = uu.x * st.x + (1.f - uu.x) * tanhf(acc[r][0] + bb.x);
            v.y = uu.y * st.y + (1.f - uu.y) * tanhf(acc[r][1] + bb.y);
            v.z = uu.z * st.z + (1.f - uu.z) * tanhf(acc[r][2] + bb.z);
            v.w = uu.w * st.w + (1.f - uu.w) * tanhf(acc[r][3] + bb.w);
            *(float4*)(&out1[idx]) = v;
            *(float4*)(&out2[idx]) = v;
        }
    }
}

extern "C" void kernel_launch(void* const* d_in, const int* in_sizes, int n_in,
                              void* d_out, int out_size, void* d_ws, size_t ws_size,
                              hipStream_t stream) {
    const float* inputs = (const float*)d_in[0];
    const float* states = (const float*)d_in[1];
    const int*   ei     = (const int*)d_in[2];
    const float* W_ru   = (const float*)d_in[3];
    const float* b_ru   = (const float*)d_in[4];
    const float* W_c    = (const float*)d_in[5];
    const float* b_c    = (const float*)d_in[6];

    float* out  = (float*)d_out;
    float* out1 = out;                             /* holds r, then new_state */
    float* out2 = out + (size_t)N_NODES * HID;     /* holds u, then new_state */

    float* ws    = (float*)d_ws;
    float* deg   = ws;
    float* agg_x = ws + AGGX_OFF;
    float* agg_s = ws + AGGS_OFF;                  /* reused as agg_rs */

    const int* src = ei;
    const int* dst = ei + N_EDGES;

    const int gemm_grid = (N_NODES + NBR - 1) / NBR;

    hipMemsetAsync(ws, 0, (size_t)WS_FLOATS * sizeof(float), stream);
    k_scatter1<<<2048, 256, 0, stream>>>(src, dst, inputs, states, deg, agg_x, agg_s);
    k_gemm_ru<<<gemm_grid, 256, 0, stream>>>(agg_x, agg_s, deg, W_ru, b_ru, out1, out2);
    hipMemsetAsync(agg_s, 0, (size_t)N_NODES * HID * sizeof(float), stream);
    k_scatter2<<<2048, 256, 0, stream>>>(src, dst, out1, states, agg_s);
    k_gemm_c<<<gemm_grid, 256, 0, stream>>>(agg_x, agg_s, deg, W_c, b_c, states,
                                            out2, out1, out2);
}

// Round 3
// 326.452 us; speedup vs baseline: 2.8227x; 2.0072x over previous
//
#include <hip/hip_runtime.h>
#include <hip/hip_bf16.h>
#include <math.h>

#define N_NODES 50000
#define N_EDGES 400000
#define F_IN    64
#define HID     128
#define FIN     192   /* F_IN + HID */
#define RU      256   /* 2*HID */

#define NSCAN   196   /* ceil(N_NODES/256) */

/* ---- ws layout (byte offsets), total ~33 MB ----
   rs    : int[N_NODES]        @ RS_OFF    (CSR starts; mutated to ends by fill)
   csr   : ushort[N_EDGES]     @ CSR_OFF   (src node id per in-edge slot)
   bsum  : int[256]            @ BSUM_OFF  (scan partials)
   A_ru  : bf16[N_NODES*FIN]   @ ARU_OFF   (normalized [agg_x | agg_s]; counts[] aliased here pre-agg)
   A_rs  : bf16[N_NODES*HID]   @ ARS_OFF   (normalized agg of r*s)                                  */
#define RS_OFF    0u
#define CSR_OFF   200192u
#define BSUM_OFF  1000448u
#define ARU_OFF   1001472u
#define ARS_OFF   (ARU_OFF + (unsigned)(N_NODES * FIN * 2))

__device__ __forceinline__ float sigf(float x) { return 1.f / (1.f + expf(-x)); }
__device__ __forceinline__ float bf2f(unsigned short h) {
    return __uint_as_float(((unsigned)h) << 16);
}
__device__ __forceinline__ unsigned short f2bf(float f) { /* RNE */
    unsigned u = __float_as_uint(f);
    return (unsigned short)((u + 0x7fff + ((u >> 16) & 1)) >> 16);
}

/* ---------------- CSR build ---------------- */
__global__ void k_hist(const int* __restrict__ dst, int* __restrict__ counts) {
    const int e = blockIdx.x * 256 + threadIdx.x;
    if (e < N_EDGES) atomicAdd(&counts[dst[e]], 1);
}

__device__ __forceinline__ int excl_scan_256(int v, int* tmp) {
    const int t = threadIdx.x;
    tmp[t] = v; __syncthreads();
    #pragma unroll
    for (int off = 1; off < 256; off <<= 1) {
        int u = (t >= off) ? tmp[t - off] : 0;
        __syncthreads();
        tmp[t] += u;
        __syncthreads();
    }
    return tmp[t] - v;
}

__global__ void k_scan_a(const int* __restrict__ counts, int* __restrict__ bsum) {
    __shared__ int tmp[256];
    const int i = blockIdx.x * 256 + threadIdx.x;
    const int v = (i < N_NODES) ? counts[i] : 0;
    excl_scan_256(v, tmp);
    if (threadIdx.x == 255) bsum[blockIdx.x] = tmp[255];
}

__global__ void k_scan_b(int* __restrict__ bsum) {
    __shared__ int tmp[256];
    const int t = threadIdx.x;
    const int v = (t < NSCAN) ? bsum[t] : 0;
    const int e = excl_scan_256(v, tmp);
    bsum[t] = e;
}

__global__ void k_scan_c(const int* __restrict__ counts, const int* __restrict__ bsum,
                         int* __restrict__ rs) {
    __shared__ int tmp[256];
    const int i = blockIdx.x * 256 + threadIdx.x;
    const int v = (i < N_NODES) ? counts[i] : 0;
    const int e = excl_scan_256(v, tmp);
    if (i < N_NODES) rs[i] = bsum[blockIdx.x] + e;
}

__global__ void k_fill(const int* __restrict__ src, const int* __restrict__ dst,
                       int* __restrict__ rs, unsigned short* __restrict__ csr) {
    const int e = blockIdx.x * 256 + threadIdx.x;
    if (e < N_EDGES) {
        const int pos = atomicAdd(&rs[dst[e]], 1);
        csr[pos] = (unsigned short)src[e];
    }
}

/* ------- agg1: one wave per node; gather x,s rows; normalize; store bf16 ------- */
__global__ __launch_bounds__(256) void k_agg1(
        const unsigned short* __restrict__ csr, const int* __restrict__ rs,
        const float* __restrict__ x, const float* __restrict__ s,
        unsigned short* __restrict__ A) {
    const int n = blockIdx.x * 4 + (threadIdx.x >> 6);
    if (n >= N_NODES) return;
    const int lane  = threadIdx.x & 63;
    const int end   = rs[n];
    const int start = n ? rs[n - 1] : 0;
    float ax = 0.f, as0 = 0.f, as1 = 0.f;
    for (int e = start; e < end; ++e) {
        const int se = csr[e];
        ax  += x[(size_t)se * F_IN + lane];
        as0 += s[(size_t)se * HID + lane];
        as1 += s[(size_t)se * HID + 64 + lane];
    }
    const float inv = 1.f / fmaxf((float)(end - start), 1.f);
    unsigned short* Ar = A + (size_t)n * FIN;
    Ar[lane]       = f2bf(ax * inv);
    Ar[64 + lane]  = f2bf(as0 * inv);
    Ar[128 + lane] = f2bf(as1 * inv);
}

/* ------- agg2: one wave per node; gather r*s; normalize; store bf16 ------- */
__global__ __launch_bounds__(256) void k_agg2(
        const unsigned short* __restrict__ csr, const int* __restrict__ rs,
        const float* __restrict__ r, const float* __restrict__ s,
        unsigned short* __restrict__ A) {
    const int n = blockIdx.x * 4 + (threadIdx.x >> 6);
    if (n >= N_NODES) return;
    const int lane  = threadIdx.x & 63;
    const int end   = rs[n];
    const int start = n ? rs[n - 1] : 0;
    float a0 = 0.f, a1 = 0.f;
    for (int e = start; e < end; ++e) {
        const int se = csr[e];
        const size_t b = (size_t)se * HID;
        a0 += r[b + lane]      * s[b + lane];
        a1 += r[b + 64 + lane] * s[b + 64 + lane];
    }
    const float inv = 1.f / fmaxf((float)(end - start), 1.f);
    unsigned short* Ar = A + (size_t)n * HID;
    Ar[lane]      = f2bf(a0 * inv);
    Ar[64 + lane] = f2bf(a1 * inv);
}

/* ------- GEMM 1: A_ru(bf16,normalized) @ W_ru + b_ru -> sigmoid -> r,u -------
 * 64 nodes/block, 256 threads, thread tile 16x4, LDS A transposed.           */
__global__ __launch_bounds__(256) void k_gemm_ru(
        const unsigned short* __restrict__ A, const float* __restrict__ W,
        const float* __restrict__ b, float* __restrict__ r_out,
        float* __restrict__ u_out) {
    __shared__ float At[FIN][68];
    const int n0 = blockIdx.x * 64;
    const int t  = threadIdx.x;
    {
        const int row = t >> 2;
        const int n   = n0 + row;
        const unsigned short* Ar = A + (size_t)n * FIN;
        #pragma unroll
        for (int j = 0; j < 12; ++j) {
            const int c = ((t & 3) * 12 + j) * 4;
            float f0 = 0.f, f1 = 0.f, f2 = 0.f, f3 = 0.f;
            if (n < N_NODES) {
                const ushort4 h = *(const ushort4*)(Ar + c);
                f0 = bf2f(h.x); f1 = bf2f(h.y); f2 = bf2f(h.z); f3 = bf2f(h.w);
            }
            At[c + 0][row] = f0; At[c + 1][row] = f1;
            At[c + 2][row] = f2; At[c + 3][row] = f3;
        }
    }
    __syncthreads();

    const int col0 = (t & 63) * 4;
    const int r0   = (t >> 6) * 16;
    float acc[16][4] = {};

    const float* Wk = W + col0;
    for (int k = 0; k < FIN; ++k) {
        const float4 w = *(const float4*)Wk;
        Wk += RU;
        float a[16];
        float4 av;
        av = *(const float4*)(&At[k][r0]);      a[0]=av.x; a[1]=av.y; a[2]=av.z; a[3]=av.w;
        av = *(const float4*)(&At[k][r0 + 4]);  a[4]=av.x; a[5]=av.y; a[6]=av.z; a[7]=av.w;
        av = *(const float4*)(&At[k][r0 + 8]);  a[8]=av.x; a[9]=av.y; a[10]=av.z; a[11]=av.w;
        av = *(const float4*)(&At[k][r0 + 12]); a[12]=av.x; a[13]=av.y; a[14]=av.z; a[15]=av.w;
        #pragma unroll
        for (int r = 0; r < 16; ++r) {
            acc[r][0] = fmaf(a[r], w.x, acc[r][0]);
            acc[r][1] = fmaf(a[r], w.y, acc[r][1]);
            acc[r][2] = fmaf(a[r], w.z, acc[r][2]);
            acc[r][3] = fmaf(a[r], w.w, acc[r][3]);
        }
    }

    const float4 bb = *(const float4*)(b + col0);
    float* outp;
    int colrel;
    if (col0 < HID) { outp = r_out; colrel = col0; }
    else            { outp = u_out; colrel = col0 - HID; }

    #pragma unroll
    for (int r = 0; r < 16; ++r) {
        const int n = n0 + r0 + r;
        if (n < N_NODES) {
            float4 v;
            v.x = sigf(acc[r][0] + bb.x);
            v.y = sigf(acc[r][1] + bb.y);
            v.z = sigf(acc[r][2] + bb.z);
            v.w = sigf(acc[r][3] + bb.w);
            *(float4*)(&outp[(size_t)n * HID + colrel]) = v;
        }
    }
}

/* ------- GEMM 2: [A_ru.x | A_rs](bf16) @ W_c + b_c -> tanh -> gate ------- */
__global__ __launch_bounds__(256) void k_gemm_c(
        const unsigned short* __restrict__ Aru, const unsigned short* __restrict__ Ars,
        const float* __restrict__ W, const float* __restrict__ b,
        const float* __restrict__ states, const float* __restrict__ u_in,
        float* __restrict__ out1, float* __restrict__ out2) {
    __shared__ float At[FIN][68];
    const int n0 = blockIdx.x * 64;
    const int t  = threadIdx.x;
    {
        const int row = t >> 2;
        const int n   = n0 + row;
        #pragma unroll
        for (int j = 0; j < 12; ++j) {
            const int c = ((t & 3) * 12 + j) * 4;
            float f0 = 0.f, f1 = 0.f, f2 = 0.f, f3 = 0.f;
            if (n < N_NODES) {
                const unsigned short* p = (c < F_IN)
                    ? (Aru + (size_t)n * FIN + c)
                    : (Ars + (size_t)n * HID + (c - F_IN));
                const ushort4 h = *(const ushort4*)p;
                f0 = bf2f(h.x); f1 = bf2f(h.y); f2 = bf2f(h.z); f3 = bf2f(h.w);
            }
            At[c + 0][row] = f0; At[c + 1][row] = f1;
            At[c + 2][row] = f2; At[c + 3][row] = f3;
        }
    }
    __syncthreads();

    const int col0 = (t & 31) * 4;
    const int r0   = (t >> 5) * 8;
    float acc[8][4] = {};

    const float* Wk = W + col0;
    for (int k = 0; k < FIN; ++k) {
        const float4 w = *(const float4*)Wk;
        Wk += HID;
        float a[8];
        float4 av;
        av = *(const float4*)(&At[k][r0]);      a[0]=av.x; a[1]=av.y; a[2]=av.z; a[3]=av.w;
        av = *(const float4*)(&At[k][r0 + 4]);  a[4]=av.x; a[5]=av.y; a[6]=av.z; a[7]=av.w;
        #pragma unroll
        for (int r = 0; r < 8; ++r) {
            acc[r][0] = fmaf(a[r], w.x, acc[r][0]);
            acc[r][1] = fmaf(a[r], w.y, acc[r][1]);
            acc[r][2] = fmaf(a[r], w.z, acc[r][2]);
            acc[r][3] = fmaf(a[r], w.w, acc[r][3]);
        }
    }

    const float4 bb = *(const float4*)(b + col0);
    #pragma unroll
    for (int r = 0; r < 8; ++r) {
        const int n = n0 + r0 + r;
        if (n < N_NODES) {
            const size_t idx = (size_t)n * HID + col0;
            const float4 st = *(const float4*)(states + idx);
            const float4 uu = *(const float4*)(u_in + idx);
            float4 v;
            v.x = uu.x * st.x + (1.f - uu.x) * tanhf(acc[r][0] + bb.x);
            v.y = uu.y * st.y + (1.f - uu.y) * tanhf(acc[r][1] + bb.y);
            v.z = uu.z * st.z + (1.f - uu.z) * tanhf(acc[r][2] + bb.z);
            v.w = uu.w * st.w + (1.f - uu.w) * tanhf(acc[r][3] + bb.w);
            *(float4*)(&out1[idx]) = v;
            *(float4*)(&out2[idx]) = v;
        }
    }
}

extern "C" void kernel_launch(void* const* d_in, const int* in_sizes, int n_in,
                              void* d_out, int out_size, void* d_ws, size_t ws_size,
                              hipStream_t stream) {
    const float* inputs = (const float*)d_in[0];
    const float* states = (const float*)d_in[1];
    const int*   ei     = (const int*)d_in[2];
    const float* W_ru   = (const float*)d_in[3];
    const float* b_ru   = (const float*)d_in[4];
    const float* W_c    = (const float*)d_in[5];
    const float* b_c    = (const float*)d_in[6];

    float* out  = (float*)d_out;
    float* out1 = out;                             /* holds r, then new_state */
    float* out2 = out + (size_t)N_NODES * HID;     /* holds u, then new_state */

    char* ws = (char*)d_ws;
    int*            rs     = (int*)(ws + RS_OFF);
    unsigned short* csr    = (unsigned short*)(ws + CSR_OFF);
    int*            bsum   = (int*)(ws + BSUM_OFF);
    unsigned short* A_ru   = (unsigned short*)(ws + ARU_OFF);
    unsigned short* A_rs   = (unsigned short*)(ws + ARS_OFF);
    int*            counts = (int*)(ws + ARU_OFF); /* aliased; dead before agg1 writes */

    const int* src = ei;
    const int* dst = ei + N_EDGES;

    const int egrid    = (N_EDGES + 255) / 256;    /* 1563 */
    const int agg_grid = (N_NODES + 3) / 4;        /* 12500 */
    const int gemm_grid = (N_NODES + 63) / 64;     /* 782  */

    hipMemsetAsync(counts, 0, N_NODES * sizeof(int), stream);
    k_hist  <<<egrid, 256, 0, stream>>>(dst, counts);
    k_scan_a<<<NSCAN, 256, 0, stream>>>(counts, bsum);
    k_scan_b<<<1,     256, 0, stream>>>(bsum);
    k_scan_c<<<NSCAN, 256, 0, stream>>>(counts, bsum, rs);
    k_fill  <<<egrid, 256, 0, stream>>>(src, dst, rs, csr);
    k_agg1  <<<agg_grid, 256, 0, stream>>>(csr, rs, inputs, states, A_ru);
    k_gemm_ru<<<gemm_grid, 256, 0, stream>>>(A_ru, W_ru, b_ru, out1, out2);
    k_agg2  <<<agg_grid, 256, 0, stream>>>(csr, rs, out1, states, A_rs);
    k_gemm_c<<<gemm_grid, 256, 0, stream>>>(A_ru, A_rs, W_c, b_c, states,
                                            out2, out1, out2);
}

// Round 4
// 261.940 us; speedup vs baseline: 3.5179x; 1.2463x over previous
//
#include <hip/hip_runtime.h>
#include <hip/hip_bf16.h>
#include <math.h>

#define N_NODES 50000
#define N_EDGES 400000
#define F_IN    64
#define HID     128
#define FIN     192   /* F_IN + HID */
#define RU      256   /* 2*HID */

#define NSCAN   196   /* ceil(N_NODES/256) */

/* ---- ws layout (byte offsets), total ~33 MB ----
   rs    : int[N_NODES]        @ RS_OFF    (CSR starts; mutated to ends by fill)
   csr   : ushort[N_EDGES]     @ CSR_OFF   (src node id per in-edge slot)
   bsum  : int[256]            @ BSUM_OFF  (scan partials)
   A_ru  : bf16[N_NODES*FIN]   @ ARU_OFF   (normalized [agg_x | agg_s]; counts[] aliased pre-agg)
   A_rs  : bf16[N_NODES*HID]   @ ARS_OFF   (normalized agg of r*s)                            */
#define RS_OFF    0u
#define CSR_OFF   200192u
#define BSUM_OFF  1000448u
#define ARU_OFF   1001472u
#define ARS_OFF   (ARU_OFF + (unsigned)(N_NODES * FIN * 2))

typedef __attribute__((ext_vector_type(8))) short short8;
typedef __attribute__((ext_vector_type(4))) float f32x4;

__device__ __forceinline__ float sigf(float x) { return 1.f / (1.f + expf(-x)); }
__device__ __forceinline__ float bf2f(unsigned short h) {
    return __uint_as_float(((unsigned)h) << 16);
}
__device__ __forceinline__ unsigned short f2bf(float f) { /* RNE */
    unsigned u = __float_as_uint(f);
    return (unsigned short)((u + 0x7fff + ((u >> 16) & 1)) >> 16);
}

/* ---------------- CSR build ---------------- */
__global__ void k_hist(const int* __restrict__ dst, int* __restrict__ counts) {
    const int e = blockIdx.x * 256 + threadIdx.x;
    if (e < N_EDGES) atomicAdd(&counts[dst[e]], 1);
}

__device__ __forceinline__ int excl_scan_256(int v, int* tmp) {
    const int t = threadIdx.x;
    tmp[t] = v; __syncthreads();
    #pragma unroll
    for (int off = 1; off < 256; off <<= 1) {
        int u = (t >= off) ? tmp[t - off] : 0;
        __syncthreads();
        tmp[t] += u;
        __syncthreads();
    }
    return tmp[t] - v;
}

__global__ void k_scan_a(const int* __restrict__ counts, int* __restrict__ bsum) {
    __shared__ int tmp[256];
    const int i = blockIdx.x * 256 + threadIdx.x;
    const int v = (i < N_NODES) ? counts[i] : 0;
    excl_scan_256(v, tmp);
    if (threadIdx.x == 255) bsum[blockIdx.x] = tmp[255];
}

__global__ void k_scan_b(int* __restrict__ bsum) {
    __shared__ int tmp[256];
    const int t = threadIdx.x;
    const int v = (t < NSCAN) ? bsum[t] : 0;
    const int e = excl_scan_256(v, tmp);
    bsum[t] = e;
}

__global__ void k_scan_c(const int* __restrict__ counts, const int* __restrict__ bsum,
                         int* __restrict__ rs) {
    __shared__ int tmp[256];
    const int i = blockIdx.x * 256 + threadIdx.x;
    const int v = (i < N_NODES) ? counts[i] : 0;
    const int e = excl_scan_256(v, tmp);
    if (i < N_NODES) rs[i] = bsum[blockIdx.x] + e;
}

__global__ void k_fill(const int* __restrict__ src, const int* __restrict__ dst,
                       int* __restrict__ rs, unsigned short* __restrict__ csr) {
    const int e = blockIdx.x * 256 + threadIdx.x;
    if (e < N_EDGES) {
        const int pos = atomicAdd(&rs[dst[e]], 1);
        csr[pos] = (unsigned short)src[e];
    }
}

/* ------- agg1: one wave per node; gather x,s rows; normalize; store bf16 ------- */
__global__ __launch_bounds__(256) void k_agg1(
        const unsigned short* __restrict__ csr, const int* __restrict__ rs,
        const float* __restrict__ x, const float* __restrict__ s,
        unsigned short* __restrict__ A) {
    const int n = blockIdx.x * 4 + (threadIdx.x >> 6);
    if (n >= N_NODES) return;
    const int lane  = threadIdx.x & 63;
    const int end   = rs[n];
    const int start = n ? rs[n - 1] : 0;
    float ax = 0.f, as0 = 0.f, as1 = 0.f;
    for (int e = start; e < end; ++e) {
        const int se = csr[e];
        ax  += x[(size_t)se * F_IN + lane];
        as0 += s[(size_t)se * HID + lane];
        as1 += s[(size_t)se * HID + 64 + lane];
    }
    const float inv = 1.f / fmaxf((float)(end - start), 1.f);
    unsigned short* Ar = A + (size_t)n * FIN;
    Ar[lane]       = f2bf(ax * inv);
    Ar[64 + lane]  = f2bf(as0 * inv);
    Ar[128 + lane] = f2bf(as1 * inv);
}

/* ------- agg2: one wave per node; gather r*s; normalize; store bf16 ------- */
__global__ __launch_bounds__(256) void k_agg2(
        const unsigned short* __restrict__ csr, const int* __restrict__ rs,
        const float* __restrict__ r, const float* __restrict__ s,
        unsigned short* __restrict__ A) {
    const int n = blockIdx.x * 4 + (threadIdx.x >> 6);
    if (n >= N_NODES) return;
    const int lane  = threadIdx.x & 63;
    const int end   = rs[n];
    const int start = n ? rs[n - 1] : 0;
    float a0 = 0.f, a1 = 0.f;
    for (int e = start; e < end; ++e) {
        const int se = csr[e];
        const size_t b = (size_t)se * HID;
        a0 += r[b + lane]      * s[b + lane];
        a1 += r[b + 64 + lane] * s[b + 64 + lane];
    }
    const float inv = 1.f / fmaxf((float)(end - start), 1.f);
    unsigned short* Ar = A + (size_t)n * HID;
    Ar[lane]      = f2bf(a0 * inv);
    Ar[64 + lane] = f2bf(a1 * inv);
}

/* ------- GEMM 1 (MFMA): A_ru(bf16) @ W_ru + b_ru -> sigmoid -> r,u -------
 * grid (782, 2): 64 rows x 128 cols per block; 4 waves, one 16-row stripe each.
 * LDS: At[64][200], Wt[128][200] bf16 (pad 200 -> 2-way max bank aliasing).  */
__global__ __launch_bounds__(256) void k_gemm_ru(
        const unsigned short* __restrict__ A, const float* __restrict__ W,
        const float* __restrict__ b, float* __restrict__ r_out,
        float* __restrict__ u_out) {
    __shared__ unsigned short At[64][200];
    __shared__ unsigned short Wt[128][200];
    const int t  = threadIdx.x;
    const int n0 = blockIdx.x * 64;
    const int cb = blockIdx.y;            /* 0 -> r half, 1 -> u half */
    const int colbase = cb * 128;

    /* stage A tile (bf16 memcpy, zero OOB rows) */
    {
        const int row = t >> 2, q = t & 3;
        const int n = n0 + row;
        #pragma unroll
        for (int j = 0; j < 6; ++j) {
            uint4 v = make_uint4(0u, 0u, 0u, 0u);
            if (n < N_NODES)
                v = *(const uint4*)(A + (size_t)n * FIN + q * 48 + j * 8);
            *(uint4*)(&At[row][q * 48 + j * 8]) = v;
        }
    }
    /* stage Wt transposed + f32->bf16: Wt[c][k] = bf16(W[k][colbase+c]) */
    {
        const int c = t & 127, kh = t >> 7;
        #pragma unroll
        for (int j = 0; j < 48; ++j) {
            const int k = kh * 96 + j * 2;
            const float w0 = W[(size_t)k * RU + colbase + c];
            const float w1 = W[(size_t)(k + 1) * RU + colbase + c];
            *(unsigned*)(&Wt[c][k]) = ((unsigned)f2bf(w1) << 16) | (unsigned)f2bf(w0);
        }
    }
    __syncthreads();

    const int lane = t & 63, wave = t >> 6;
    const int fr = lane & 15;             /* frag row (A) / col (B) */
    const int fk = (lane >> 4) * 8;       /* frag k offset          */
    const unsigned short* pa = &At[wave * 16 + fr][fk];

    f32x4 acc[8] = {};
    #pragma unroll
    for (int k0 = 0; k0 < 6; ++k0) {
        const short8 a = *(const short8*)(pa + k0 * 32);
        #pragma unroll
        for (int ct = 0; ct < 8; ++ct) {
            const short8 bw = *(const short8*)(&Wt[ct * 16 + fr][fk + k0 * 32]);
            acc[ct] = __builtin_amdgcn_mfma_f32_16x16x32_bf16(a, bw, acc[ct], 0, 0, 0);
        }
    }

    float* outp = cb ? u_out : r_out;
    const int rbase = n0 + wave * 16 + (lane >> 4) * 4;
    #pragma unroll
    for (int ct = 0; ct < 8; ++ct) {
        const int colrel = ct * 16 + fr;
        const float bias = b[colbase + colrel];
        #pragma unroll
        for (int i = 0; i < 4; ++i) {
            const int n = rbase + i;
            if (n < N_NODES)
                outp[(size_t)n * HID + colrel] = sigf(acc[ct][i] + bias);
        }
    }
}

/* ------- GEMM 2 (MFMA): [A_ru[:, :64] | A_rs](bf16) @ W_c + b_c -> tanh -> gate ---- */
__global__ __launch_bounds__(256) void k_gemm_c(
        const unsigned short* __restrict__ Aru, const unsigned short* __restrict__ Ars,
        const float* __restrict__ W, const float* __restrict__ b,
        const float* __restrict__ states, const float* __restrict__ u_in,
        float* __restrict__ out1, float* __restrict__ out2) {
    __shared__ unsigned short At[64][200];
    __shared__ unsigned short Wt[128][200];
    const int t  = threadIdx.x;
    const int n0 = blockIdx.x * 64;

    /* stage A tile: cols 0..63 from A_ru, 64..191 from A_rs (16B units) */
    #pragma unroll
    for (int j = 0; j < 6; ++j) {
        const int idx = t + 256 * j;          /* 0..1535 uint4 slots */
        const int row = idx / 24, u = idx - row * 24;
        const int n = n0 + row;
        uint4 v = make_uint4(0u, 0u, 0u, 0u);
        if (n < N_NODES)
            v = (u < 8) ? *(const uint4*)(Aru + (size_t)n * FIN + u * 8)
                        : *(const uint4*)(Ars + (size_t)n * HID + (u - 8) * 8);
        *(uint4*)(&At[row][u * 8]) = v;
    }
    /* stage Wt transposed + f32->bf16 (pitch HID) */
    {
        const int c = t & 127, kh = t >> 7;
        #pragma unroll
        for (int j = 0; j < 48; ++j) {
            const int k = kh * 96 + j * 2;
            const float w0 = W[(size_t)k * HID + c];
            const float w1 = W[(size_t)(k + 1) * HID + c];
            *(unsigned*)(&Wt[c][k]) = ((unsigned)f2bf(w1) << 16) | (unsigned)f2bf(w0);
        }
    }
    __syncthreads();

    const int lane = t & 63, wave = t >> 6;
    const int fr = lane & 15;
    const int fk = (lane >> 4) * 8;
    const unsigned short* pa = &At[wave * 16 + fr][fk];

    f32x4 acc[8] = {};
    #pragma unroll
    for (int k0 = 0; k0 < 6; ++k0) {
        const short8 a = *(const short8*)(pa + k0 * 32);
        #pragma unroll
        for (int ct = 0; ct < 8; ++ct) {
            const short8 bw = *(const short8*)(&Wt[ct * 16 + fr][fk + k0 * 32]);
            acc[ct] = __builtin_amdgcn_mfma_f32_16x16x32_bf16(a, bw, acc[ct], 0, 0, 0);
        }
    }

    const int rbase = n0 + wave * 16 + (lane >> 4) * 4;
    #pragma unroll
    for (int ct = 0; ct < 8; ++ct) {
        const int colrel = ct * 16 + fr;
        const float bias = b[colrel];
        #pragma unroll
        for (int i = 0; i < 4; ++i) {
            const int n = rbase + i;
            if (n < N_NODES) {
                const size_t idx = (size_t)n * HID + colrel;
                const float c  = tanhf(acc[ct][i] + bias);
                const float uu = u_in[idx];
                const float st = states[idx];
                const float ns = uu * st + (1.f - uu) * c;
                out1[idx] = ns;
                out2[idx] = ns;
            }
        }
    }
}

extern "C" void kernel_launch(void* const* d_in, const int* in_sizes, int n_in,
                              void* d_out, int out_size, void* d_ws, size_t ws_size,
                              hipStream_t stream) {
    const float* inputs = (const float*)d_in[0];
    const float* states = (const float*)d_in[1];
    const int*   ei     = (const int*)d_in[2];
    const float* W_ru   = (const float*)d_in[3];
    const float* b_ru   = (const float*)d_in[4];
    const float* W_c    = (const float*)d_in[5];
    const float* b_c    = (const float*)d_in[6];

    float* out  = (float*)d_out;
    float* out1 = out;                             /* holds r, then new_state */
    float* out2 = out + (size_t)N_NODES * HID;     /* holds u, then new_state */

    char* ws = (char*)d_ws;
    int*            rs     = (int*)(ws + RS_OFF);
    unsigned short* csr    = (unsigned short*)(ws + CSR_OFF);
    int*            bsum   = (int*)(ws + BSUM_OFF);
    unsigned short* A_ru   = (unsigned short*)(ws + ARU_OFF);
    unsigned short* A_rs   = (unsigned short*)(ws + ARS_OFF);
    int*            counts = (int*)(ws + ARU_OFF); /* aliased; dead before agg1 writes */

    const int* src = ei;
    const int* dst = ei + N_EDGES;

    const int egrid     = (N_EDGES + 255) / 256;   /* 1563  */
    const int agg_grid  = (N_NODES + 3) / 4;       /* 12500 */
    const int gemm_grid = (N_NODES + 63) / 64;     /* 782   */

    hipMemsetAsync(counts, 0, N_NODES * sizeof(int), stream);
    k_hist  <<<egrid, 256, 0, stream>>>(dst, counts);
    k_scan_a<<<NSCAN, 256, 0, stream>>>(counts, bsum);
    k_scan_b<<<1,     256, 0, stream>>>(bsum);
    k_scan_c<<<NSCAN, 256, 0, stream>>>(counts, bsum, rs);
    k_fill  <<<egrid, 256, 0, stream>>>(src, dst, rs, csr);
    k_agg1  <<<agg_grid, 256, 0, stream>>>(csr, rs, inputs, states, A_ru);
    k_gemm_ru<<<dim3(gemm_grid, 2), 256, 0, stream>>>(A_ru, W_ru, b_ru, out1, out2);
    k_agg2  <<<agg_grid, 256, 0, stream>>>(csr, rs, out1, states, A_rs);
    k_gemm_c<<<gemm_grid, 256, 0, stream>>>(A_ru, A_rs, W_c, b_c, states,
                                            out2, out1, out2);
}